// Round 13
// baseline (79.801 us; speedup 1.0000x reference)
//
#include <hip/hip_runtime.h>
#include <hip/hip_bf16.h>
#include <math.h>

// Problem constants
#define BB   256
#define INW  512
#define HH   1024
#define OUTW 512
#define SS   512
#define WD   256
#define P_READ  262
#define P_WRITE 774
#define RW_LD   1056   // 272 (read pad) + 784 (write pad)
#define W_OFF   272
#define H2LD 1056      // h2 row stride: 1024 h | 1 one | 31 zeros
#define M1LD 1056      // M1 row stride: 1024 j | 1 bias | 31 zeros

typedef __attribute__((ext_vector_type(8))) short bf16x8;
typedef __attribute__((ext_vector_type(4))) float f32x4;

__device__ __forceinline__ float sigmoidf(float x) { return 1.f / (1.f + expf(-x)); }
__device__ __forceinline__ float softplusf(float x) { return (x > 20.f) ? x : log1pf(expf(x)); }

// f32x8 -> bf16x8 via hardware cvt (compiler emits v_cvt_pk_bf16_f32; m240: do NOT hand-roll)
__device__ __forceinline__ bf16x8 cvt8(const float* p) {
    float4 lo = *reinterpret_cast<const float4*>(p);
    float4 hi = *reinterpret_cast<const float4*>(p + 4);
    union { bf16x8 v; __hip_bfloat16 h[8]; } u;
    u.h[0] = __float2bfloat16(lo.x); u.h[1] = __float2bfloat16(lo.y);
    u.h[2] = __float2bfloat16(lo.z); u.h[3] = __float2bfloat16(lo.w);
    u.h[4] = __float2bfloat16(hi.x); u.h[5] = __float2bfloat16(hi.y);
    u.h[6] = __float2bfloat16(hi.z); u.h[7] = __float2bfloat16(hi.w);
    return u.v;
}

// ============ S1: k_front — gates GEMM+LSTM | M1 GEMM (+norm fold) | memT | pads ============
#define GB_GATES 1024
#define GB_M1    4160      // 2 matrices x 32 s-tiles x 65 j-tiles
#define GB_MEMT  64
#define GB_H2P   (GB_GATES + GB_M1 + GB_MEMT)       // 1 block
#define GB_M1P   (GB_H2P + 1)                        // 4 blocks
#define GB_FRONT (GB_M1P + 4)

__global__ __launch_bounds__(64)
void k_front(const float* __restrict__ x, const float* __restrict__ W_ih,
             const float* __restrict__ b_ih, const float* __restrict__ b_hh,
             const float* __restrict__ W_read, const float* __restrict__ b_read,
             const float* __restrict__ W_write, const float* __restrict__ b_write,
             const float* __restrict__ mem,
             __hip_bfloat16* __restrict__ h2, __hip_bfloat16* __restrict__ M1b,
             __hip_bfloat16* __restrict__ memT_b)
{
    const int bid = blockIdx.x;
    const int lane = threadIdx.x;
    const int r = lane & 15, q = lane >> 4;

    if (bid < GB_GATES) {
        // gates: compact i|g|o rows (f-gate dead: c0=0), x cols 0..511 (rv0=0)
        const int bn = (bid & 63) * 16;    // j tile
        const int bm = (bid >> 6) * 16;    // b tile
        const float* axp = x    + (size_t)(bm + r) * INW + q * 8;
        const float* bip = W_ih + (size_t)(bn + r) * 768 + q * 8;
        const float* bgp = W_ih + (size_t)(2048 + bn + r) * 768 + q * 8;
        const float* bop = W_ih + (size_t)(3072 + bn + r) * 768 + q * 8;
        f32x4 ai = {0.f,0.f,0.f,0.f}, ag = ai, ao = ai;
        #pragma unroll
        for (int k = 0; k < INW; k += 32) {
            bf16x8 a = cvt8(axp + k);
            ai = __builtin_amdgcn_mfma_f32_16x16x32_bf16(a, cvt8(bip + k), ai, 0, 0, 0);
            ag = __builtin_amdgcn_mfma_f32_16x16x32_bf16(a, cvt8(bgp + k), ag, 0, 0, 0);
            ao = __builtin_amdgcn_mfma_f32_16x16x32_bf16(a, cvt8(bop + k), ao, 0, 0, 0);
        }
        const int j = bn + r;
        const float bii = b_ih[j] + b_hh[j];
        const float big = b_ih[2048 + j] + b_hh[2048 + j];
        const float bio = b_ih[3072 + j] + b_hh[3072 + j];
        #pragma unroll
        for (int jj = 0; jj < 4; ++jj) {
            int b = bm + q * 4 + jj;
            float c = sigmoidf(ai[jj] + bii) * tanhf(ag[jj] + big);
            h2[(size_t)b * H2LD + j] = __float2bfloat16(sigmoidf(ao[jj] + bio) * tanhf(c));
        }
        return;
    }
    if (bid < GB_GATES + GB_M1) {
        // M1[s, j] = sum_w mem[s,w] * W[w,j]  (+ bias row j=1024), rows divided by ||mem_s||
        int m = bid - GB_GATES;
        int mat = (m >= 2080) ? 1 : 0;
        int t = m - mat * 2080;
        int st = t / 65, jt = t % 65;
        const int bm = st * 16, bn = jt * 16;
        const float* Wsrc = mat ? W_write : W_read;
        const float* bias = mat ? b_write : b_read;
        const int j = bn + r;
        const float* ap0 = mem + (size_t)(bm + r) * WD + q * 8;
        f32x4 acc = {0.f,0.f,0.f,0.f};
        float nn = 0.f;
        #pragma unroll
        for (int ki = 0; ki < 8; ++ki) {
            const int kk = ki * 32;
            float4 lo = *reinterpret_cast<const float4*>(ap0 + kk);
            float4 hi = *reinterpret_cast<const float4*>(ap0 + kk + 4);
            nn += lo.x*lo.x + lo.y*lo.y + lo.z*lo.z + lo.w*lo.w
                + hi.x*hi.x + hi.y*hi.y + hi.z*hi.z + hi.w*hi.w;
            union { bf16x8 v; __hip_bfloat16 h[8]; } ua;
            ua.h[0]=__float2bfloat16(lo.x); ua.h[1]=__float2bfloat16(lo.y);
            ua.h[2]=__float2bfloat16(lo.z); ua.h[3]=__float2bfloat16(lo.w);
            ua.h[4]=__float2bfloat16(hi.x); ua.h[5]=__float2bfloat16(hi.y);
            ua.h[6]=__float2bfloat16(hi.z); ua.h[7]=__float2bfloat16(hi.w);
            union { bf16x8 v; __hip_bfloat16 h[8]; } ub;
            if (j < 1024) {
                // scattered-but-coalesced: 16 r-lanes hit consecutive floats of one row
                const float* ws = Wsrc + (size_t)(kk + q * 8) * 1024 + j;
                #pragma unroll
                for (int e = 0; e < 8; ++e)
                    ub.h[e] = __float2bfloat16(ws[(size_t)e * 1024]);
            } else if (j == 1024) {
                #pragma unroll
                for (int e = 0; e < 8; ++e)
                    ub.h[e] = __float2bfloat16(bias[kk + q * 8 + e]);
            } else {
                #pragma unroll
                for (int e = 0; e < 8; ++e) ub.h[e] = __float2bfloat16(0.f);
            }
            acc = __builtin_amdgcn_mfma_f32_16x16x32_bf16(ua.v, ub.v, acc, 0, 0, 0);
        }
        // full slot norm^2 for row bm+r (reduce over the 4 q-lanes sharing r)
        nn += __shfl_xor(nn, 16, 64);
        nn += __shfl_xor(nn, 32, 64);
        #pragma unroll
        for (int jj = 0; jj < 4; ++jj) {
            float n2 = __shfl(nn, q * 4 + jj, 64);       // norm^2 of row bm+q*4+jj
            float inv = 1.f / fmaxf(sqrtf(n2), 1e-8f);
            int srow = mat * 512 + bm + q * 4 + jj;
            M1b[(size_t)srow * M1LD + bn + r] = __float2bfloat16(acc[jj] * inv);
        }
        return;
    }
    if (bid < GB_GATES + GB_M1 + GB_MEMT) {
        int wb = (bid - GB_GATES - GB_M1) * 4;
        for (int i = 0; i < 4; ++i) {
            int wr = wb + i;
            for (int s = lane; s < SS; s += 64)
                memT_b[(size_t)wr * SS + s] = __float2bfloat16(mem[(size_t)s * WD + wr]);
        }
        return;
    }
    if (bid == GB_H2P) {
        // h2 pad: col 1024 = 1, cols 1025..1055 = 0
        for (int idx = lane; idx < 256 * 32; idx += 64) {
            int row = idx >> 5, c = idx & 31;
            h2[(size_t)row * H2LD + 1024 + c] = __float2bfloat16(c == 0 ? 1.f : 0.f);
        }
        return;
    }
    {
        // M1 pad: cols 1040..1055 of all 1024 rows (j-tile 64 covers 1024..1039)
        int pb = bid - GB_M1P;     // 0..3
        for (int idx = lane + pb * 4096; idx < (pb + 1) * 4096; idx += 64 * 1) {
            int row = idx >> 4, c = idx & 15;
            M1b[(size_t)row * M1LD + 1040 + c] = __float2bfloat16(0.f);
        }
    }
}

// ============ S2: k_mid — rpwp GEMM | out_h GEMM | num GEMM ============
__global__ __launch_bounds__(64)
void k_mid(const __hip_bfloat16* __restrict__ h2, const __hip_bfloat16* __restrict__ M1b,
           const float* __restrict__ W_read, const float* __restrict__ b_read,
           const float* __restrict__ W_write, const float* __restrict__ b_write,
           const float* __restrict__ W_out, const float* __restrict__ b_out,
           float* __restrict__ rpwp, float* __restrict__ out, float* __restrict__ numd)
{
    const int bid = blockIdx.x;
    const int lane = threadIdx.x;
    const int r = lane & 15, q = lane >> 4;
    const bf16x8 z8 = {0,0,0,0,0,0,0,0};

    if (bid < 1056) {
        // rpwp = h @ [Wr pad | Ww pad]^T + bias
        const int nt = bid % 66, mt = bid / 66;
        const int bm = mt * 16, bn = nt * 16;
        const int brow = bn + r;
        bool valid;
        const float* bsrc;
        if (brow < W_OFF) { valid = (brow < P_READ); bsrc = W_read + (size_t)(valid ? brow : 0) * 1024; }
        else { int w2 = brow - W_OFF; valid = (w2 < P_WRITE); bsrc = W_write + (size_t)(valid ? w2 : 0) * 1024; }
        bsrc += q * 8;
        const __hip_bfloat16* ap = h2 + (size_t)(bm + r) * H2LD + q * 8;
        f32x4 a0 = {0.f,0.f,0.f,0.f}, a1 = a0;
        #pragma unroll 8
        for (int k = 0; k < 512; k += 32) {
            bf16x8 b0 = valid ? cvt8(bsrc + k) : z8;
            bf16x8 b1 = valid ? cvt8(bsrc + 512 + k) : z8;
            a0 = __builtin_amdgcn_mfma_f32_16x16x32_bf16(
                *reinterpret_cast<const bf16x8*>(ap + k), b0, a0, 0, 0, 0);
            a1 = __builtin_amdgcn_mfma_f32_16x16x32_bf16(
                *reinterpret_cast<const bf16x8*>(ap + 512 + k), b1, a1, 0, 0, 0);
        }
        const int col = bn + r;
        float bv = 0.f;
        if (col < W_OFF) { if (col < P_READ) bv = b_read[col]; }
        else { int wc = col - W_OFF; if (wc < P_WRITE) bv = b_write[wc]; }
        #pragma unroll
        for (int j = 0; j < 4; ++j) {
            int m = bm + q * 4 + j;
            rpwp[(size_t)m * RW_LD + col] = a0[j] + a1[j] + bv;
        }
    } else if (bid < 1568) {
        // out_h = h @ W_out[:, :1024]^T + b_out
        const int o = bid - 1056;
        const int nt = o & 31, mt = o >> 5;
        const int bm = mt * 16, bn = nt * 16;
        const __hip_bfloat16* ap = h2 + (size_t)(bm + r) * H2LD + q * 8;
        const float* bp = W_out + (size_t)(bn + r) * 1280 + q * 8;
        f32x4 a0 = {0.f,0.f,0.f,0.f}, a1 = a0;
        #pragma unroll 8
        for (int k = 0; k < 512; k += 32) {
            a0 = __builtin_amdgcn_mfma_f32_16x16x32_bf16(
                *reinterpret_cast<const bf16x8*>(ap + k), cvt8(bp + k), a0, 0, 0, 0);
            a1 = __builtin_amdgcn_mfma_f32_16x16x32_bf16(
                *reinterpret_cast<const bf16x8*>(ap + 512 + k), cvt8(bp + 512 + k), a1, 0, 0, 0);
        }
        const int col = bn + r;
        const float bv = b_out[col];
        #pragma unroll
        for (int j = 0; j < 4; ++j) {
            int m = bm + q * 4 + j;
            out[(size_t)m * OUTW + col] = a0[j] + a1[j] + bv;
        }
    } else {
        // num = h2 @ M1^T  -> numd[b, s'] (s'<512 read, s'>=512 write), already /||mem_s||
        const int o = bid - 1568;
        const int nt = o & 63, mt = o >> 6;
        const int bm = mt * 16, bn = nt * 16;
        const __hip_bfloat16* ap = h2 + (size_t)(bm + r) * H2LD + q * 8;
        const __hip_bfloat16* bp = M1b + (size_t)(bn + r) * M1LD + q * 8;
        f32x4 a0 = {0.f,0.f,0.f,0.f}, a1 = a0;
        #pragma unroll 8
        for (int k = 0; k < 512; k += 32)
            a0 = __builtin_amdgcn_mfma_f32_16x16x32_bf16(
                *reinterpret_cast<const bf16x8*>(ap + k),
                *reinterpret_cast<const bf16x8*>(bp + k), a0, 0, 0, 0);
        #pragma unroll
        for (int k = 512; k < 1056; k += 32)
            a1 = __builtin_amdgcn_mfma_f32_16x16x32_bf16(
                *reinterpret_cast<const bf16x8*>(ap + k),
                *reinterpret_cast<const bf16x8*>(bp + k), a1, 0, 0, 0);
        const int col = bn + r;
        #pragma unroll
        for (int j = 0; j < 4; ++j) {
            int m = bm + q * 4 + j;
            numd[(size_t)m * 1024 + col] = a0[j] + a1[j];
        }
    }
}

// ============ S3: fused addressing + A12 pack + t3 ============
__device__ __forceinline__ void redpair_sum(float& a, float& b, volatile float* redA, volatile float* redB) {
    #pragma unroll
    for (int off = 32; off > 0; off >>= 1) { a += __shfl_down(a, off, 64); b += __shfl_down(b, off, 64); }
    int wid = threadIdx.x >> 6;
    __syncthreads();
    if ((threadIdx.x & 63) == 0) { redA[wid] = a; redB[wid] = b; }
    __syncthreads();
    a = redA[0]+redA[1]+redA[2]+redA[3]+redA[4]+redA[5]+redA[6]+redA[7];
    b = redB[0]+redB[1]+redB[2]+redB[3]+redB[4]+redB[5]+redB[6]+redB[7];
}
__device__ __forceinline__ void redpair_max(float& a, float& b, volatile float* redA, volatile float* redB) {
    #pragma unroll
    for (int off = 32; off > 0; off >>= 1) { a = fmaxf(a, __shfl_down(a, off, 64)); b = fmaxf(b, __shfl_down(b, off, 64)); }
    int wid = threadIdx.x >> 6;
    __syncthreads();
    if ((threadIdx.x & 63) == 0) { redA[wid] = a; redB[wid] = b; }
    __syncthreads();
    a = fmaxf(fmaxf(fmaxf(redA[0],redA[1]),fmaxf(redA[2],redA[3])),fmaxf(fmaxf(redA[4],redA[5]),fmaxf(redA[6],redA[7])));
    b = fmaxf(fmaxf(fmaxf(redB[0],redB[1]),fmaxf(redB[2],redB[3])),fmaxf(fmaxf(redB[4],redB[5]),fmaxf(redB[6],redB[7])));
}

__global__ __launch_bounds__(512)
void address_fused(const float* __restrict__ rpwp, const float* __restrict__ numd,
                   __hip_bfloat16* __restrict__ A12, float* __restrict__ t3)
{
    const int b = blockIdx.x;
    const int t = threadIdx.x;            // slot
    const float* pr = rpwp + (size_t)b * RW_LD;
    const float* pw = pr + W_OFF;

    __shared__ float redA[8], redB[8];
    __shared__ float bufr[SS], bufw[SS];

    float beta_r  = softplusf(pr[WD]);
    float gate_r  = sigmoidf(pr[WD + 1]);
    float r0 = pr[WD+2], r1 = pr[WD+3], r2 = pr[WD+4];
    float rmx = fmaxf(r0, fmaxf(r1, r2));
    float re0 = expf(r0-rmx), re1 = expf(r1-rmx), re2 = expf(r2-rmx);
    float rinv = 1.f / (re0+re1+re2);
    float shr0 = re0*rinv, shr1 = re1*rinv, shr2 = re2*rinv;
    float gamma_r = 1.f + softplusf(pr[WD + 5]);

    float beta_w  = softplusf(pw[WD]);
    float gate_w  = sigmoidf(pw[WD + 1]);
    float w0 = pw[WD+2], w1 = pw[WD+3], w2 = pw[WD+4];
    float wmx = fmaxf(w0, fmaxf(w1, w2));
    float we0 = expf(w0-wmx), we1 = expf(w1-wmx), we2 = expf(w2-wmx);
    float winv = 1.f / (we0+we1+we2);
    float shw0 = we0*winv, shw1 = we1*winv, shw2 = we2*winv;
    float gamma_w = 1.f + softplusf(pw[WD + 5]);

    {
        float kv = (t < WD) ? pr[t] : pw[t - WD];
        float vv = kv * kv;
        #pragma unroll
        for (int off = 32; off > 0; off >>= 1) vv += __shfl_down(vv, off, 64);
        int wid = t >> 6;
        if ((t & 63) == 0) redA[wid] = vv;
        __syncthreads();
    }
    float knr = fmaxf(sqrtf(redA[0]+redA[1]+redA[2]+redA[3]), 1e-8f);
    float knw = fmaxf(sqrtf(redA[4]+redA[5]+redA[6]+redA[7]), 1e-8f);
    __syncthreads();

    float sim_r = numd[(size_t)b * 1024 + t]       / knr * beta_r;
    float sim_w = numd[(size_t)b * 1024 + 512 + t] / knw * beta_w;

    float mr = sim_r, mw = sim_w;
    redpair_max(mr, mw, redA, redB);
    float exr = expf(sim_r - mr), exw = expf(sim_w - mw);
    float sr = exr, sw = exw;
    redpair_sum(sr, sw, redA, redB);
    float cwr = exr / sr, cww = exw / sw;

    float onehot = (t == 0) ? 1.f : 0.f;
    float gwr = gate_r * cwr + (1.f - gate_r) * onehot;
    float gww = gate_w * cww + (1.f - gate_w) * onehot;
    __syncthreads();
    bufr[t] = gwr; bufw[t] = gww;
    __syncthreads();

    int tm = (t + SS - 1) & (SS - 1), tp = (t + 1) & (SS - 1);
    float swr = shr0 * bufr[tm] + shr1 * gwr + shr2 * bufr[tp];
    float sww = shw0 * bufw[tm] + shw1 * gww + shw2 * bufw[tp];

    float spr = powf(fmaxf(swr, 0.f), gamma_r), spw = powf(fmaxf(sww, 0.f), gamma_w);
    float ssr = spr, ssw = spw;
    redpair_sum(ssr, ssw, redA, redB);
    float rfin = spr / (ssr + 1e-6f);
    float wfin = spw / (ssw + 1e-6f);

    float prod = rfin * wfin;
    A12[(size_t)b * SS + t] = __float2bfloat16(rfin);
    A12[(size_t)(256 + b) * SS + t] = __float2bfloat16(prod);
    float tp3 = prod, dummy = 0.f;
    redpair_sum(tp3, dummy, redA, redB);
    if (t == 0) t3[b] = tp3;
}

// ============ S4: t12 GEMM + rv epilogue -> rv_b ============
__global__ __launch_bounds__(64)
void gemm_t12rv(const __hip_bfloat16* __restrict__ A12,
                const __hip_bfloat16* __restrict__ memT_b,
                const float* __restrict__ rpwp, const float* __restrict__ t3,
                __hip_bfloat16* __restrict__ rv_b)
{
    const int l = threadIdx.x;
    const int bn = blockIdx.x * 16;   // w
    const int bm = blockIdx.y * 16;   // b
    const int r = l & 15, q = l >> 4;
    const __hip_bfloat16* a1 = A12 + (size_t)(bm + r) * SS + q * 8;
    const __hip_bfloat16* a2 = a1 + (size_t)256 * SS;
    const __hip_bfloat16* bp = memT_b + (size_t)(bn + r) * SS + q * 8;
    f32x4 acc1 = {0.f,0.f,0.f,0.f}, acc2 = acc1;
    #pragma unroll
    for (int k = 0; k < SS; k += 32) {
        bf16x8 bb = *reinterpret_cast<const bf16x8*>(bp + k);
        acc1 = __builtin_amdgcn_mfma_f32_16x16x32_bf16(*reinterpret_cast<const bf16x8*>(a1 + k), bb, acc1, 0, 0, 0);
        acc2 = __builtin_amdgcn_mfma_f32_16x16x32_bf16(*reinterpret_cast<const bf16x8*>(a2 + k), bb, acc2, 0, 0, 0);
    }
    const int w = bn + r;
    #pragma unroll
    for (int j = 0; j < 4; ++j) {
        int b = bm + q * 4 + j;
        const float* row = rpwp + (size_t)b * RW_LD;
        float e = sigmoidf(row[W_OFF + P_READ + w]);
        float a = tanhf(row[W_OFF + P_READ + WD + w]);
        float rv = acc1[j] - e * acc2[j] + a * t3[b];
        rv_b[(size_t)b * WD + w] = __float2bfloat16(rv);
    }
}

// ============ S5: out += rv @ Wo_rv^T (inline weight cvt) ============
__global__ __launch_bounds__(64)
void k_outrv(const __hip_bfloat16* __restrict__ rv_b,
             const float* __restrict__ W_out,
             float* __restrict__ out)
{
    const int l = threadIdx.x;
    const int bn = blockIdx.x * 16;   // out col
    const int bm = blockIdx.y * 16;   // batch
    const int r = l & 15, q = l >> 4;
    const __hip_bfloat16* ap = rv_b + (size_t)(bm + r) * WD + q * 8;
    const float* bp = W_out + (size_t)(bn + r) * 1280 + 1024 + q * 8;
    f32x4 acc = {0.f,0.f,0.f,0.f};
    #pragma unroll
    for (int k = 0; k < WD; k += 32)
        acc = __builtin_amdgcn_mfma_f32_16x16x32_bf16(
            *reinterpret_cast<const bf16x8*>(ap + k), cvt8(bp + k), acc, 0, 0, 0);
    const int col = bn + r;
    #pragma unroll
    for (int j = 0; j < 4; ++j) {
        int m = bm + q * 4 + j;
        out[(size_t)m * OUTW + col] += acc[j];
    }
}

// ---------------- host launcher ----------------
extern "C" void kernel_launch(void* const* d_in, const int* in_sizes, int n_in,
                              void* d_out, int out_size, void* d_ws, size_t ws_size,
                              hipStream_t stream)
{
    const float* x       = (const float*)d_in[0];
    const float* W_ih    = (const float*)d_in[1];
    const float* b_ih    = (const float*)d_in[2];
    const float* b_hh    = (const float*)d_in[4];
    const float* W_read  = (const float*)d_in[5];
    const float* b_read  = (const float*)d_in[6];
    const float* W_write = (const float*)d_in[7];
    const float* b_write = (const float*)d_in[8];
    const float* W_out   = (const float*)d_in[9];
    const float* b_out   = (const float*)d_in[10];
    const float* mem     = (const float*)d_in[11];

    float* ws = (float*)d_ws;
    float* rpwp = ws;                 // 270336
    float* numd = ws + 270336;        // 262144
    float* t3   = ws + 532480;        // 256
    __hip_bfloat16* bfb = (__hip_bfloat16*)(ws + 532736);
    __hip_bfloat16* h2     = bfb;                 // 270336
    __hip_bfloat16* M1b    = bfb + 270336;        // 1081344
    __hip_bfloat16* memT_b = bfb + 1351680;       // 131072
    __hip_bfloat16* A12    = bfb + 1482752;       // 262144
    __hip_bfloat16* rv_b   = bfb + 1744896;       // 65536
    float* out = (float*)d_out;

    // S1: gates+LSTM || M1 (num factorization, norms folded) || memT || pads
    k_front<<<GB_FRONT, 64, 0, stream>>>(x, W_ih, b_ih, b_hh, W_read, b_read,
                                         W_write, b_write, mem, h2, M1b, memT_b);
    // S2: rpwp || out_h || num
    k_mid<<<2592, 64, 0, stream>>>(h2, M1b, W_read, b_read, W_write, b_write,
                                   W_out, b_out, rpwp, out, numd);
    // S3: addressing + A12 + t3
    address_fused<<<BB, 512, 0, stream>>>(rpwp, numd, A12, t3);
    // S4: t12 GEMM + rv
    gemm_t12rv<<<dim3(16, 16), 64, 0, stream>>>(A12, memT_b, rpwp, t3, rv_b);
    // S5: out += rv @ Wo_rv^T
    k_outrv<<<dim3(32, 16), 64, 0, stream>>>(rv_b, W_out, out);
}

// Round 14
// 61.136 us; speedup vs baseline: 1.3053x; 1.3053x over previous
//
#include <hip/hip_runtime.h>
#include <hip/hip_bf16.h>
#include <math.h>

// Problem constants
#define BB   256
#define INW  512
#define HH   1024
#define OUTW 512
#define SS   512
#define WD   256
#define P_READ  262
#define P_WRITE 774
#define RW_LD   1056   // 272 (read pad) + 784 (write pad)
#define W_OFF   272

typedef __attribute__((ext_vector_type(8))) short bf16x8;
typedef __attribute__((ext_vector_type(4))) float f32x4;

__device__ __forceinline__ float sigmoidf(float x) { return 1.f / (1.f + expf(-x)); }
__device__ __forceinline__ float softplusf(float x) { return (x > 20.f) ? x : log1pf(expf(x)); }

// f32x8 -> bf16x8 via hardware cvt (compiler emits v_cvt_pk_bf16_f32)
__device__ __forceinline__ bf16x8 cvt8(const float* p) {
    float4 lo = *reinterpret_cast<const float4*>(p);
    float4 hi = *reinterpret_cast<const float4*>(p + 4);
    union { bf16x8 v; __hip_bfloat16 h[8]; } u;
    u.h[0] = __float2bfloat16(lo.x); u.h[1] = __float2bfloat16(lo.y);
    u.h[2] = __float2bfloat16(lo.z); u.h[3] = __float2bfloat16(lo.w);
    u.h[4] = __float2bfloat16(hi.x); u.h[5] = __float2bfloat16(hi.y);
    u.h[6] = __float2bfloat16(hi.z); u.h[7] = __float2bfloat16(hi.w);
    return u.v;
}
__device__ __forceinline__ void st_bf4f(__hip_bfloat16* d, float4 v) {
    union { ushort4 u4; __hip_bfloat16 h[4]; } u;
    u.h[0] = __float2bfloat16(v.x); u.h[1] = __float2bfloat16(v.y);
    u.h[2] = __float2bfloat16(v.z); u.h[3] = __float2bfloat16(v.w);
    *reinterpret_cast<ushort4*>(d) = u.u4;
}

// ============ S1: k_front — gates GEMM+LSTM (inline cvt) | converters | mem norms ============
// converter 4-element groups
#define NWRW4 (RW_LD*1024/4)     // 270336
#define NWO4  (512*1280/4)       // 163840
#define NMB4  (512*256/4)        // 32768
#define NMT4  (256*512/4)        // 32768
#define NCVT4 (NWRW4+NWO4+NMB4+NMT4)          // 499712
#define GB_GATES 1024
#define GB_CVT   (NCVT4/256)                   // 1952 blocks (64 thr x 4 groups? -> 256 groups/block)
#define GB_NORM  512
#define GB_FRONT (GB_GATES + GB_CVT + GB_NORM)

__global__ __launch_bounds__(64)
void k_front(const float* __restrict__ x, const float* __restrict__ W_ih,
             const float* __restrict__ b_ih, const float* __restrict__ b_hh,
             const float* __restrict__ W_read, const float* __restrict__ W_write,
             const float* __restrict__ W_out, const float* __restrict__ mem,
             __hip_bfloat16* __restrict__ h_b,
             __hip_bfloat16* __restrict__ Wrw_p, __hip_bfloat16* __restrict__ Wo_b,
             __hip_bfloat16* __restrict__ mem_b, __hip_bfloat16* __restrict__ memT_b,
             float* __restrict__ mem_norm)
{
    const int bid = blockIdx.x;
    const int lane = threadIdx.x;

    if (bid < GB_GATES) {
        // gates: compact i|g|o rows (f-gate dead: c0=0), x cols 0..511 (rv0=0)
        const int bn = (bid & 63) * 16;    // j tile
        const int bm = (bid >> 6) * 16;    // b tile
        const int r = lane & 15, q = lane >> 4;
        const float* axp = x    + (size_t)(bm + r) * INW + q * 8;
        const float* bip = W_ih + (size_t)(bn + r) * 768 + q * 8;
        const float* bgp = W_ih + (size_t)(2048 + bn + r) * 768 + q * 8;
        const float* bop = W_ih + (size_t)(3072 + bn + r) * 768 + q * 8;
        f32x4 ai = {0.f,0.f,0.f,0.f}, ag = ai, ao = ai;
        #pragma unroll
        for (int k = 0; k < INW; k += 32) {
            bf16x8 a = cvt8(axp + k);
            ai = __builtin_amdgcn_mfma_f32_16x16x32_bf16(a, cvt8(bip + k), ai, 0, 0, 0);
            ag = __builtin_amdgcn_mfma_f32_16x16x32_bf16(a, cvt8(bgp + k), ag, 0, 0, 0);
            ao = __builtin_amdgcn_mfma_f32_16x16x32_bf16(a, cvt8(bop + k), ao, 0, 0, 0);
        }
        const int j = bn + r;
        const float bii = b_ih[j] + b_hh[j];
        const float big = b_ih[2048 + j] + b_hh[2048 + j];
        const float bio = b_ih[3072 + j] + b_hh[3072 + j];
        #pragma unroll
        for (int jj = 0; jj < 4; ++jj) {
            int b = bm + q * 4 + jj;
            float c = sigmoidf(ai[jj] + bii) * tanhf(ag[jj] + big);
            h_b[(size_t)b * HH + j] = __float2bfloat16(sigmoidf(ao[jj] + bio) * tanhf(c));
        }
        return;
    }
    if (bid < GB_GATES + GB_CVT) {
        // converters: 256 4-elem groups per block (4 per thread iteration x 4 iters)
        long g0 = (long)(bid - GB_GATES) * 256 + lane;
        #pragma unroll
        for (int it = 0; it < 4; ++it) {
            long g = g0 + it * 64;
            if (g < NWRW4) {
                long i = g * 4;
                int r = (int)(i >> 10), c = (int)(i & 1023);
                float4 v = make_float4(0.f, 0.f, 0.f, 0.f);
                if (r < W_OFF) { if (r < P_READ) v = *reinterpret_cast<const float4*>(W_read + (size_t)r * 1024 + c); }
                else { int wr = r - W_OFF; if (wr < P_WRITE) v = *reinterpret_cast<const float4*>(W_write + (size_t)wr * 1024 + c); }
                st_bf4f(Wrw_p + i, v);
                continue;
            }
            long g2 = g - NWRW4;
            if (g2 < NWO4) {
                long i = g2 * 4;
                st_bf4f(Wo_b + i, *reinterpret_cast<const float4*>(W_out + i));
                continue;
            }
            g2 -= NWO4;
            if (g2 < NMB4) {
                long i = g2 * 4;
                st_bf4f(mem_b + i, *reinterpret_cast<const float4*>(mem + i));
                continue;
            }
            g2 -= NMB4;
            {
                long i = g2 * 4;
                int w = (int)(i >> 9), s = (int)(i & 511);
                float4 v = make_float4(mem[(size_t)s * 256 + w], mem[(size_t)(s + 1) * 256 + w],
                                       mem[(size_t)(s + 2) * 256 + w], mem[(size_t)(s + 3) * 256 + w]);
                st_bf4f(memT_b + i, v);
            }
        }
        return;
    }
    {
        // mem row norms: one row per block, 64 lanes x 4 elems
        int s = bid - GB_GATES - GB_CVT;
        float4 v = *reinterpret_cast<const float4*>(mem + (size_t)s * WD + lane * 4);
        float vv = v.x*v.x + v.y*v.y + v.z*v.z + v.w*v.w;
        #pragma unroll
        for (int off = 32; off > 0; off >>= 1) vv += __shfl_down(vv, off, 64);
        if (lane == 0) mem_norm[s] = fmaxf(sqrtf(vv), 1e-8f);
    }
}

// ============ S2: dual GEMM (rpwp + keys harvest || out h-part) — bf16, R9-proven ============
__global__ __launch_bounds__(64)
void gemm_dual(const __hip_bfloat16* __restrict__ h_b,
               const __hip_bfloat16* __restrict__ Wrw_p,
               const __hip_bfloat16* __restrict__ Wo_b,
               const float* __restrict__ b_read, const float* __restrict__ b_write,
               const float* __restrict__ b_out,
               float* __restrict__ rpwp, float* __restrict__ out,
               __hip_bfloat16* __restrict__ keys)
{
    const int bid = blockIdx.x;
    const int lane = threadIdx.x;
    const int r = lane & 15, q = lane >> 4;
    int bm, bn, ldb;
    const __hip_bfloat16* B;
    if (bid < 1056) { int nt = bid % 66, mt = bid / 66; bm = mt * 16; bn = nt * 16; B = Wrw_p; ldb = HH; }
    else { int o = bid - 1056; int nt = o & 31, mt = o >> 5; bm = mt * 16; bn = nt * 16; B = Wo_b; ldb = 1280; }

    const __hip_bfloat16* ap = h_b + (size_t)(bm + r) * HH + q * 8;
    const __hip_bfloat16* bp = B + (size_t)(bn + r) * ldb + q * 8;
    f32x4 a0 = {0.f,0.f,0.f,0.f}, a1 = a0;
    #pragma unroll 8
    for (int k = 0; k < 512; k += 32) {
        a0 = __builtin_amdgcn_mfma_f32_16x16x32_bf16(
            *reinterpret_cast<const bf16x8*>(ap + k),
            *reinterpret_cast<const bf16x8*>(bp + k), a0, 0, 0, 0);
        a1 = __builtin_amdgcn_mfma_f32_16x16x32_bf16(
            *reinterpret_cast<const bf16x8*>(ap + 512 + k),
            *reinterpret_cast<const bf16x8*>(bp + 512 + k), a1, 0, 0, 0);
    }
    const int col = bn + r;
    if (bid < 1056) {
        float bv = 0.f;
        if (col < W_OFF) { if (col < P_READ) bv = b_read[col]; }
        else { int wc = col - W_OFF; if (wc < P_WRITE) bv = b_write[wc]; }
        #pragma unroll
        for (int j = 0; j < 4; ++j) {
            int m = bm + q * 4 + j;
            float v = a0[j] + a1[j] + bv;
            rpwp[(size_t)m * RW_LD + col] = v;
            // keys: rows 0..255 = read keys, rows 256..511 = write keys
            if (col < WD)
                keys[(size_t)m * WD + col] = __float2bfloat16(v);
            else if (col >= W_OFF && col < W_OFF + WD)
                keys[(size_t)(256 + m) * WD + (col - W_OFF)] = __float2bfloat16(v);
        }
    } else {
        const float bv = b_out[col];
        #pragma unroll
        for (int j = 0; j < 4; ++j) {
            int m = bm + q * 4 + j;
            out[(size_t)m * OUTW + col] = a0[j] + a1[j] + bv;
        }
    }
}

// ============ S3: num GEMM [512x512] = keys @ mem^T, * (1/mem_norm[col]) — R9-proven ============
__global__ __launch_bounds__(64)
void gemm_num(const __hip_bfloat16* __restrict__ keys,
              const __hip_bfloat16* __restrict__ mem_b,
              const float* __restrict__ mem_norm,
              float* __restrict__ numd)
{
    const int l = threadIdx.x;
    const int bn = blockIdx.x * 16;   // slot
    const int bm = blockIdx.y * 16;   // key row
    const int r = l & 15, q = l >> 4;
    const __hip_bfloat16* ap = keys + (size_t)(bm + r) * WD + q * 8;
    const __hip_bfloat16* bp = mem_b + (size_t)(bn + r) * WD + q * 8;
    f32x4 acc = {0.f,0.f,0.f,0.f};
    #pragma unroll
    for (int k = 0; k < WD; k += 32)
        acc = __builtin_amdgcn_mfma_f32_16x16x32_bf16(
            *reinterpret_cast<const bf16x8*>(ap + k),
            *reinterpret_cast<const bf16x8*>(bp + k), acc, 0, 0, 0);
    const int col = bn + r;
    const float inv = 1.f / mem_norm[col];
    #pragma unroll
    for (int j = 0; j < 4; ++j)
        numd[(size_t)(bm + q * 4 + j) * SS + col] = acc[j] * inv;
}

// ============ S4: fused addressing + A12 pack + t3 — R9-proven ============
__device__ __forceinline__ void redpair_sum(float& a, float& b, volatile float* redA, volatile float* redB) {
    #pragma unroll
    for (int off = 32; off > 0; off >>= 1) { a += __shfl_down(a, off, 64); b += __shfl_down(b, off, 64); }
    int wid = threadIdx.x >> 6;
    __syncthreads();
    if ((threadIdx.x & 63) == 0) { redA[wid] = a; redB[wid] = b; }
    __syncthreads();
    a = redA[0]+redA[1]+redA[2]+redA[3]+redA[4]+redA[5]+redA[6]+redA[7];
    b = redB[0]+redB[1]+redB[2]+redB[3]+redB[4]+redB[5]+redB[6]+redB[7];
}
__device__ __forceinline__ void redpair_max(float& a, float& b, volatile float* redA, volatile float* redB) {
    #pragma unroll
    for (int off = 32; off > 0; off >>= 1) { a = fmaxf(a, __shfl_down(a, off, 64)); b = fmaxf(b, __shfl_down(b, off, 64)); }
    int wid = threadIdx.x >> 6;
    __syncthreads();
    if ((threadIdx.x & 63) == 0) { redA[wid] = a; redB[wid] = b; }
    __syncthreads();
    a = fmaxf(fmaxf(fmaxf(redA[0],redA[1]),fmaxf(redA[2],redA[3])),fmaxf(fmaxf(redA[4],redA[5]),fmaxf(redA[6],redA[7])));
    b = fmaxf(fmaxf(fmaxf(redB[0],redB[1]),fmaxf(redB[2],redB[3])),fmaxf(fmaxf(redB[4],redB[5]),fmaxf(redB[6],redB[7])));
}

__global__ __launch_bounds__(512)
void address_fused(const float* __restrict__ rpwp, const float* __restrict__ numd,
                   __hip_bfloat16* __restrict__ A12, float* __restrict__ t3)
{
    const int b = blockIdx.x;
    const int t = threadIdx.x;            // slot
    const float* pr = rpwp + (size_t)b * RW_LD;
    const float* pw = pr + W_OFF;

    __shared__ float redA[8], redB[8];
    __shared__ float bufr[SS], bufw[SS];

    float beta_r  = softplusf(pr[WD]);
    float gate_r  = sigmoidf(pr[WD + 1]);
    float r0 = pr[WD+2], r1 = pr[WD+3], r2 = pr[WD+4];
    float rmx = fmaxf(r0, fmaxf(r1, r2));
    float re0 = expf(r0-rmx), re1 = expf(r1-rmx), re2 = expf(r2-rmx);
    float rinv = 1.f / (re0+re1+re2);
    float shr0 = re0*rinv, shr1 = re1*rinv, shr2 = re2*rinv;
    float gamma_r = 1.f + softplusf(pr[WD + 5]);

    float beta_w  = softplusf(pw[WD]);
    float gate_w  = sigmoidf(pw[WD + 1]);
    float w0 = pw[WD+2], w1 = pw[WD+3], w2 = pw[WD+4];
    float wmx = fmaxf(w0, fmaxf(w1, w2));
    float we0 = expf(w0-wmx), we1 = expf(w1-wmx), we2 = expf(w2-wmx);
    float winv = 1.f / (we0+we1+we2);
    float shw0 = we0*winv, shw1 = we1*winv, shw2 = we2*winv;
    float gamma_w = 1.f + softplusf(pw[WD + 5]);

    {
        float kv = (t < WD) ? pr[t] : pw[t - WD];
        float vv = kv * kv;
        #pragma unroll
        for (int off = 32; off > 0; off >>= 1) vv += __shfl_down(vv, off, 64);
        int wid = t >> 6;
        if ((t & 63) == 0) redA[wid] = vv;
        __syncthreads();
    }
    float knr = fmaxf(sqrtf(redA[0]+redA[1]+redA[2]+redA[3]), 1e-8f);
    float knw = fmaxf(sqrtf(redA[4]+redA[5]+redA[6]+redA[7]), 1e-8f);
    __syncthreads();

    float sim_r = numd[(size_t)b * SS + t]         / knr * beta_r;
    float sim_w = numd[(size_t)(256 + b) * SS + t] / knw * beta_w;

    float mr = sim_r, mw = sim_w;
    redpair_max(mr, mw, redA, redB);
    float exr = expf(sim_r - mr), exw = expf(sim_w - mw);
    float sr = exr, sw = exw;
    redpair_sum(sr, sw, redA, redB);
    float cwr = exr / sr, cww = exw / sw;

    float onehot = (t == 0) ? 1.f : 0.f;
    float gwr = gate_r * cwr + (1.f - gate_r) * onehot;
    float gww = gate_w * cww + (1.f - gate_w) * onehot;
    __syncthreads();
    bufr[t] = gwr; bufw[t] = gww;
    __syncthreads();

    int tm = (t + SS - 1) & (SS - 1), tp = (t + 1) & (SS - 1);
    float swr = shr0 * bufr[tm] + shr1 * gwr + shr2 * bufr[tp];
    float sww = shw0 * bufw[tm] + shw1 * gww + shw2 * bufw[tp];

    float spr = powf(fmaxf(swr, 0.f), gamma_r), spw = powf(fmaxf(sww, 0.f), gamma_w);
    float ssr = spr, ssw = spw;
    redpair_sum(ssr, ssw, redA, redB);
    float rfin = spr / (ssr + 1e-6f);
    float wfin = spw / (ssw + 1e-6f);

    float prod = rfin * wfin;
    A12[(size_t)b * SS + t] = __float2bfloat16(rfin);
    A12[(size_t)(256 + b) * SS + t] = __float2bfloat16(prod);
    float tp3 = prod, dummy = 0.f;
    redpair_sum(tp3, dummy, redA, redB);
    if (t == 0) t3[b] = tp3;
}

// ============ S5: t12 GEMM + rv epilogue -> rv_b — R9-proven ============
__global__ __launch_bounds__(64)
void gemm_t12rv(const __hip_bfloat16* __restrict__ A12,
                const __hip_bfloat16* __restrict__ memT_b,
                const float* __restrict__ rpwp, const float* __restrict__ t3,
                __hip_bfloat16* __restrict__ rv_b)
{
    const int l = threadIdx.x;
    const int bn = blockIdx.x * 16;   // w
    const int bm = blockIdx.y * 16;   // b
    const int r = l & 15, q = l >> 4;
    const __hip_bfloat16* a1 = A12 + (size_t)(bm + r) * SS + q * 8;
    const __hip_bfloat16* a2 = a1 + (size_t)256 * SS;
    const __hip_bfloat16* bp = memT_b + (size_t)(bn + r) * SS + q * 8;
    f32x4 acc1 = {0.f,0.f,0.f,0.f}, acc2 = acc1;
    #pragma unroll
    for (int k = 0; k < SS; k += 32) {
        bf16x8 bb = *reinterpret_cast<const bf16x8*>(bp + k);
        acc1 = __builtin_amdgcn_mfma_f32_16x16x32_bf16(*reinterpret_cast<const bf16x8*>(a1 + k), bb, acc1, 0, 0, 0);
        acc2 = __builtin_amdgcn_mfma_f32_16x16x32_bf16(*reinterpret_cast<const bf16x8*>(a2 + k), bb, acc2, 0, 0, 0);
    }
    const int w = bn + r;
    #pragma unroll
    for (int j = 0; j < 4; ++j) {
        int b = bm + q * 4 + j;
        const float* row = rpwp + (size_t)b * RW_LD;
        float e = sigmoidf(row[W_OFF + P_READ + w]);
        float a = tanhf(row[W_OFF + P_READ + WD + w]);
        float rv = acc1[j] - e * acc2[j] + a * t3[b];
        rv_b[(size_t)b * WD + w] = __float2bfloat16(rv);
    }
}

// ============ S6: out += rv_b @ Wo_rv^T — R9-proven ============
__global__ __launch_bounds__(64)
void gemm_outrv(const __hip_bfloat16* __restrict__ rv_b,
                const __hip_bfloat16* __restrict__ Wo_b,
                float* __restrict__ out)
{
    const int l = threadIdx.x;
    const int bn = blockIdx.x * 16;   // out col
    const int bm = blockIdx.y * 16;   // batch
    const int r = l & 15, q = l >> 4;
    const __hip_bfloat16* ap = rv_b + (size_t)(bm + r) * WD + q * 8;
    const __hip_bfloat16* bp = Wo_b + (size_t)(bn + r) * 1280 + 1024 + q * 8;
    f32x4 acc = {0.f,0.f,0.f,0.f};
    #pragma unroll
    for (int k = 0; k < WD; k += 32)
        acc = __builtin_amdgcn_mfma_f32_16x16x32_bf16(
            *reinterpret_cast<const bf16x8*>(ap + k),
            *reinterpret_cast<const bf16x8*>(bp + k), acc, 0, 0, 0);
    const int col = bn + r;
    #pragma unroll
    for (int j = 0; j < 4; ++j) {
        int m = bm + q * 4 + j;
        out[(size_t)m * OUTW + col] += acc[j];
    }
}

// ---------------- host launcher ----------------
extern "C" void kernel_launch(void* const* d_in, const int* in_sizes, int n_in,
                              void* d_out, int out_size, void* d_ws, size_t ws_size,
                              hipStream_t stream)
{
    const float* x       = (const float*)d_in[0];
    const float* W_ih    = (const float*)d_in[1];
    const float* b_ih    = (const float*)d_in[2];
    const float* b_hh    = (const float*)d_in[4];
    const float* W_read  = (const float*)d_in[5];
    const float* b_read  = (const float*)d_in[6];
    const float* W_write = (const float*)d_in[7];
    const float* b_write = (const float*)d_in[8];
    const float* W_out   = (const float*)d_in[9];
    const float* b_out   = (const float*)d_in[10];
    const float* mem     = (const float*)d_in[11];

    float* ws = (float*)d_ws;
    float* rpwp     = ws;                 // 270336
    float* numd     = ws + 270336;        // 262144
    float* t3       = ws + 532480;        // 256
    float* mem_norm = ws + 532736;        // 512
    __hip_bfloat16* bfb = (__hip_bfloat16*)(ws + 533248);
    __hip_bfloat16* Wrw_p  = bfb;                 // 1081344
    __hip_bfloat16* Wo_b   = bfb + 1081344;       // 655360
    __hip_bfloat16* mem_b  = bfb + 1736704;       // 131072
    __hip_bfloat16* memT_b = bfb + 1867776;       // 131072
    __hip_bfloat16* h_b    = bfb + 1998848;       // 262144
    __hip_bfloat16* keys   = bfb + 2260992;       // 131072
    __hip_bfloat16* A12    = bfb + 2392064;       // 262144
    __hip_bfloat16* rv_b   = bfb + 2654208;       // 65536
    float* out = (float*)d_out;

    // S1: gates (inline cvt) + converters + mem norms
    k_front<<<GB_FRONT, 64, 0, stream>>>(x, W_ih, b_ih, b_hh, W_read, W_write,
                                         W_out, mem, h_b, Wrw_p, Wo_b, mem_b,
                                         memT_b, mem_norm);
    // S2: rpwp GEMM (+keys) || out h-part GEMM
    gemm_dual<<<1568, 64, 0, stream>>>(h_b, Wrw_p, Wo_b, b_read, b_write, b_out,
                                       rpwp, out, keys);
    // S3: num = keys @ mem^T (/slot-norm)
    gemm_num<<<dim3(32, 32), 64, 0, stream>>>(keys, mem_b, mem_norm, numd);
    // S4: addressing + A12 + t3
    address_fused<<<BB, 512, 0, stream>>>(rpwp, numd, A12, t3);
    // S5: t12 GEMM + rv -> rv_b
    gemm_t12rv<<<dim3(16, 16), 64, 0, stream>>>(A12, memT_b, rpwp, t3, rv_b);
    // S6: out += rv_b @ Wo_rv^T
    gemm_outrv<<<dim3(32, 16), 64, 0, stream>>>(rv_b, Wo_b, out);
}